// Round 6
// baseline (249.403 us; speedup 1.0000x reference)
//
#include <hip/hip_runtime.h>

// RNN: h_{t+1} = relu(x_t*W_ih^T + b_ih + b_hh + W_hh·h_t), out = fc(h_T).
// B=4096, T=1000, H=20.
//
// R21: R20 (4 lanes/batch, rotation gather, fold-free) with the two wall
// killers fixed. Model (fits R16..R20): harness enforces busy*f ~= 1.07GHz
// per CU when all 4 SIMDs loaded (throttle) -> 16-lane family capped at
// ~146-152us; 1-wave/CU configs run at full 2.4GHz un-throttled and their
// harness == their wall. R20's wall (244us, 58% SIMD duty) was ruined by
// (a) an 11-deep serial pk_fma chain (~110cy/step latency) and (b) a 29KB
// unrolled body ~ L1I size with no co-tenant wave to warm it.
// Fixes: 4 MAC chains of 5-6 levels (C0 = init+own-h, starts pre-gather;
// C1/C2/C3 = one rotation each) + 2-level merge; 8-step loop body (~6KB),
// loop overhead on the scalar pipe. Issue ~280cy/step -> 117us @ 2.4GHz
// at full duty; predict ~125-140us rocprof ~= harness.

#define TT 1000

typedef float v2f __attribute__((ext_vector_type(2)));

// one weight column: rows 5j..5j+4 packed (r0,r1),(r2,r3),r4 = 5 VGPRs
struct Col { v2f p01, p23; float v4; };

#define PIN(v)  asm volatile("" : "+v"(v))
__device__ __forceinline__ void pinc(Col& c) {
    PIN(c.p01); PIN(c.p23); PIN(c.v4);
}
__device__ __forceinline__ void keepc(const Col& c) {
    asm volatile("" :: "v"(c.p01), "v"(c.p23), "v"(c.v4));
}

// quad_perm rotate-by-r: lane j reads lane (j+r)&3
#define QP_ROR1 0x39   // [1,2,3,0]
#define QP_ROR2 0x4E   // [2,3,0,1]
#define QP_ROR3 0x93   // [3,0,1,2]

template <int CTRL>
__device__ __forceinline__ float dpp_mov(float v) {
    // old=0 + bound_ctrl -> v_mov_b32_dpp
    return __int_as_float(__builtin_amdgcn_update_dpp(
        0, __float_as_int(v), CTRL, 0xF, 0xF, true));
}

__global__ void
__attribute__((amdgpu_flat_work_group_size(64, 64), amdgpu_waves_per_eu(1, 1)))
rnn_os_kernel(const float* __restrict__ x,
              const float* __restrict__ W_ih,
              const float* __restrict__ W_hh,
              const float* __restrict__ b_ih,
              const float* __restrict__ b_hh,
              const float* __restrict__ fc_w,
              const float* __restrict__ fc_b,
              float* __restrict__ out) {
    const int tid = blockIdx.x * 64 + threadIdx.x;
    const int b   = tid >> 2;     // batch element (4 lanes per batch)
    const int j   = tid & 3;      // lane in quad: owns rows 5j..5j+4

    // --- weight slots, rotation-ordered: slot s multiplies h element
    //     h[5*((j+s/5)&3) + s%5]; weight col index follows the same map.
    Col c0, c1, c2, c3, c4, c5, c6, c7, c8, c9,
        c10, c11, c12, c13, c14, c15, c16, c17, c18, c19;
#define LOADS(ck, s)                                                          \
    { const int own = (j + (s) / 5) & 3;                                      \
      const int ci  = own * 5 + (s) % 5;                                      \
      (ck).p01 = (v2f){ W_hh[(j * 5 + 0) * 20 + ci],                          \
                        W_hh[(j * 5 + 1) * 20 + ci] };                        \
      (ck).p23 = (v2f){ W_hh[(j * 5 + 2) * 20 + ci],                          \
                        W_hh[(j * 5 + 3) * 20 + ci] };                        \
      (ck).v4  =        W_hh[(j * 5 + 4) * 20 + ci]; }
    LOADS(c0, 0)   LOADS(c1, 1)   LOADS(c2, 2)   LOADS(c3, 3)   LOADS(c4, 4)
    LOADS(c5, 5)   LOADS(c6, 6)   LOADS(c7, 7)   LOADS(c8, 8)   LOADS(c9, 9)
    LOADS(c10, 10) LOADS(c11, 11) LOADS(c12, 12) LOADS(c13, 13) LOADS(c14, 14)
    LOADS(c15, 15) LOADS(c16, 16) LOADS(c17, 17) LOADS(c18, 18) LOADS(c19, 19)
#undef LOADS

    // input weights + combined bias for own rows (counted exactly once)
    Col wie, bie;
    {
        const float* pw = W_ih + j * 5;
        const float* p1 = b_ih + j * 5;
        const float* p2 = b_hh + j * 5;
        wie.p01 = (v2f){ pw[0], pw[1] };
        wie.p23 = (v2f){ pw[2], pw[3] };
        wie.v4  = pw[4];
        bie.p01 = (v2f){ p1[0] + p2[0], p1[1] + p2[1] };
        bie.p23 = (v2f){ p1[2] + p2[2], p1[3] + p2[3] };
        bie.v4  = p1[4] + p2[4];
    }

    pinc(c0); pinc(c1); pinc(c2); pinc(c3); pinc(c4);
    pinc(c5); pinc(c6); pinc(c7); pinc(c8); pinc(c9);
    pinc(c10); pinc(c11); pinc(c12); pinc(c13); pinc(c14);
    pinc(c15); pinc(c16); pinc(c17); pinc(c18); pinc(c19);
    pinc(wie); pinc(bie);

    v2f h01 = {0.f, 0.f}, h23 = {0.f, 0.f};
    float h4 = 0.f;

    const float* __restrict__ xb = x + (size_t)b * TT;

    // one timestep: 3 rotation gathers; FOUR independent MAC chains of
    // 5-6 levels; 2-level merge tree; relu. Critical path ~100cy << issue.
    auto step1 = [&](float xt) {
        // gathers (VALU dpp movs, on the critical path -> issue first)
        v2f g101, g123; float g14;
        v2f g201, g223; float g24;
        v2f g301, g323; float g34;
        g101.x = dpp_mov<QP_ROR1>(h01.x); g101.y = dpp_mov<QP_ROR1>(h01.y);
        g123.x = dpp_mov<QP_ROR1>(h23.x); g123.y = dpp_mov<QP_ROR1>(h23.y);
        g14    = dpp_mov<QP_ROR1>(h4);
        g201.x = dpp_mov<QP_ROR2>(h01.x); g201.y = dpp_mov<QP_ROR2>(h01.y);
        g223.x = dpp_mov<QP_ROR2>(h23.x); g223.y = dpp_mov<QP_ROR2>(h23.y);
        g24    = dpp_mov<QP_ROR2>(h4);
        g301.x = dpp_mov<QP_ROR3>(h01.x); g301.y = dpp_mov<QP_ROR3>(h01.y);
        g323.x = dpp_mov<QP_ROR3>(h23.x); g323.y = dpp_mov<QP_ROR3>(h23.y);
        g34    = dpp_mov<QP_ROR3>(h4);

#define MACC(A01, A23, a4, hs, hk, ck)                                  \
        A01 = __builtin_elementwise_fma(hs, (ck).p01, A01);             \
        A23 = __builtin_elementwise_fma(hs, (ck).p23, A23);             \
        a4  = __builtin_fmaf(hk, (ck).v4, a4);

        // chain C0: init + own slots 0..4 (no gather dependence)
        const v2f xs = {xt, xt};
        v2f  P01 = __builtin_elementwise_fma(xs, wie.p01, bie.p01);
        v2f  P23 = __builtin_elementwise_fma(xs, wie.p23, bie.p23);
        float p4 = __builtin_fmaf(xt, wie.v4, bie.v4);
        MACC(P01, P23, p4, h01.xx, h01.x, c0)
        MACC(P01, P23, p4, h01.yy, h01.y, c1)
        MACC(P01, P23, p4, h23.xx, h23.x, c2)
        MACC(P01, P23, p4, h23.yy, h23.y, c3)
        { const v2f s = {h4, h4};   MACC(P01, P23, p4, s, h4, c4) }

        // chain C1: rot1 slots 5..9
        v2f  Q01 = g101.xx * c5.p01;
        v2f  Q23 = g101.xx * c5.p23;
        float q4 = g101.x  * c5.v4;
        MACC(Q01, Q23, q4, g101.yy, g101.y, c6)
        MACC(Q01, Q23, q4, g123.xx, g123.x, c7)
        MACC(Q01, Q23, q4, g123.yy, g123.y, c8)
        { const v2f s = {g14, g14}; MACC(Q01, Q23, q4, s, g14, c9) }

        // chain C2: rot2 slots 10..14
        v2f  R01 = g201.xx * c10.p01;
        v2f  R23 = g201.xx * c10.p23;
        float r4 = g201.x  * c10.v4;
        MACC(R01, R23, r4, g201.yy, g201.y, c11)
        MACC(R01, R23, r4, g223.xx, g223.x, c12)
        MACC(R01, R23, r4, g223.yy, g223.y, c13)
        { const v2f s = {g24, g24}; MACC(R01, R23, r4, s, g24, c14) }

        // chain C3: rot3 slots 15..19
        v2f  S01 = g301.xx * c15.p01;
        v2f  S23 = g301.xx * c15.p23;
        float s4 = g301.x  * c15.v4;
        MACC(S01, S23, s4, g301.yy, g301.y, c16)
        MACC(S01, S23, s4, g323.xx, g323.x, c17)
        MACC(S01, S23, s4, g323.yy, g323.y, c18)
        { const v2f s = {g34, g34}; MACC(S01, S23, s4, s, g34, c19) }
#undef MACC

        // merge tree (2 levels) + relu
        const v2f z = {0.f, 0.f};
        v2f  M01 = P01 + Q01;           // v_pk_add_f32
        v2f  M23 = P23 + Q23;
        float m4 = p4 + q4;
        v2f  N01 = R01 + S01;
        v2f  N23 = R23 + S23;
        float n4 = r4 + s4;
        v2f  A01 = M01 + N01;
        v2f  A23 = M23 + N23;
        float a4 = m4 + n4;
        h01 = __builtin_elementwise_max(A01, z);   // v_pk_max_f32
        h23 = __builtin_elementwise_max(A23, z);
        h4  = fmaxf(a4, 0.f);
    };

#define RUN4(Q) { step1(Q.x); step1(Q.y); step1(Q.z); step1(Q.w); }

    // --- 8-step loop body (~6KB, I$-resident), 2 float4 double-buffered,
    //     prefetch distance 8 steps (~1000cy). Loop overhead = SALU only.
    float4 A = *(const float4*)(xb);       // steps 0..3
    float4 B = *(const float4*)(xb + 4);   // steps 4..7

    for (int it = 0; it < 124; ++it) {
        const float* p = xb + it * 8;
        RUN4(A)                            // steps 8it .. 8it+3
        A = *(const float4*)(p + 8);       // steps 8it+8 .. +11
        RUN4(B)                            // steps 8it+4 .. 8it+7
        B = *(const float4*)(p + 12);      // steps 8it+12 .. +15
    }
    // it=123 loaded steps 992..995 (A) and 996..999 (B)
    RUN4(A)                                // steps 992..995
    RUN4(B)                                // steps 996..999

#undef RUN4

    keepc(c0); keepc(c1); keepc(c2); keepc(c3); keepc(c4);
    keepc(c5); keepc(c6); keepc(c7); keepc(c8); keepc(c9);
    keepc(c10); keepc(c11); keepc(c12); keepc(c13); keepc(c14);
    keepc(c15); keepc(c16); keepc(c17); keepc(c18); keepc(c19);
    keepc(wie); keepc(bie);

    // Final: lane j holds h[5j..5j+4]. Dot with fc_w rows, reduce over quad.
    float dot;
    {
        const float* pf = fc_w + j * 5;
        dot = h01.x * pf[0];
        dot = __builtin_fmaf(h01.y, pf[1], dot);
        dot = __builtin_fmaf(h23.x, pf[2], dot);
        dot = __builtin_fmaf(h23.y, pf[3], dot);
        dot = __builtin_fmaf(h4,    pf[4], dot);
    }
    dot += __shfl_xor(dot, 1, 4);
    dot += __shfl_xor(dot, 2, 4);

    if (j == 0)
        out[b] = dot + fc_b[0];
}

extern "C" void kernel_launch(void* const* d_in, const int* in_sizes, int n_in,
                              void* d_out, int out_size, void* d_ws, size_t ws_size,
                              hipStream_t stream) {
    const float* x    = (const float*)d_in[0];
    const float* W_ih = (const float*)d_in[1];
    const float* W_hh = (const float*)d_in[2];
    const float* b_ih = (const float*)d_in[3];
    const float* b_hh = (const float*)d_in[4];
    const float* fc_w = (const float*)d_in[5];
    const float* fc_b = (const float*)d_in[6];
    float* out = (float*)d_out;

    // 4096 batches * 4 lanes = 16384 threads; 64-thread blocks -> 256
    // single-wave blocks, one per CU (1 of 4 SIMDs busy -> no throttle).
    const int block = 64;
    const int grid  = (4096 * 4) / block;  // 256 blocks
    rnn_os_kernel<<<grid, block, 0, stream>>>(x, W_ih, W_hh, b_ih, b_hh,
                                              fc_w, fc_b, out);
}

// Round 7
// 247.289 us; speedup vs baseline: 1.0085x; 1.0085x over previous
//
#include <hip/hip_runtime.h>

// RNN: h_{t+1} = relu(x_t*W_ih^T + b_ih + b_hh + W_hh·h_t), out = fc(h_T).
// B=4096, T=1000, H=20.
//
// R22: batch-PAIR packed R16. Model (fits R16..R21): harness = max(wall,
// VALU-work cap ~225 G instr/s at full occupancy). Quad/8-lane family is
// dead (256-512 waves x single-wave issue cadence ~4cy -> >=140us floor).
// R16 (146.7us best) sits AT the cap with 33.8M instr. This kernel keeps
// R16's 16-lane alternating-role scheme bit-exactly per batch but packs
// TWO batches into every v2f: all MACs become v_pk_fma_f32 (op_sel splat
// weights, R16-proven free), folds stay scalar v_add_f32_dpp on the 10
// halves. 57 instr/step for 8 batches = 7.1/batch vs R16's 8.25 ->
// 29.2M total (-14%). 512 waves, 2/CU. Predict harness ~127-137us.

#define TT 1000

typedef float v2f __attribute__((ext_vector_type(2)));

// One role's weights, per lane. Batch pair lives in v2f halves of STATE;
// weights are value-paired purely so splats are op_sel swizzles:
//   w01[r]=(whh[r][0],whh[r][1]); w23[r]=(whh[r][2],whh[r][3]);
//   w4a=(whh[0][4],whh[1][4]); w4b=(whh[2][4],whh[3][4]); w4c=(whh[4][4],dup)
//   wih01=(wih[0],wih[1]) ... bias row-paired the same way (masked).
struct WRole {
    v2f w01[5], w23[5];
    v2f w4a, w4b, w4c;
    v2f wih01, wih23, wih4;
    v2f b01, b23, b4;
};

#define PIN(v)  asm volatile("" : "+v"(v))
__device__ __forceinline__ void pinw(WRole& W) {
    PIN(W.w01[0]); PIN(W.w01[1]); PIN(W.w01[2]); PIN(W.w01[3]); PIN(W.w01[4]);
    PIN(W.w23[0]); PIN(W.w23[1]); PIN(W.w23[2]); PIN(W.w23[3]); PIN(W.w23[4]);
    PIN(W.w4a); PIN(W.w4b); PIN(W.w4c);
    PIN(W.wih01); PIN(W.wih23); PIN(W.wih4);
    PIN(W.b01); PIN(W.b23); PIN(W.b4);
}
__device__ __forceinline__ void keepw(const WRole& W) {
    asm volatile("" :: "v"(W.w01[0]), "v"(W.w01[1]), "v"(W.w01[2]),
                       "v"(W.w01[3]), "v"(W.w01[4]));
    asm volatile("" :: "v"(W.w23[0]), "v"(W.w23[1]), "v"(W.w23[2]),
                       "v"(W.w23[3]), "v"(W.w23[4]));
    asm volatile("" :: "v"(W.w4a), "v"(W.w4b), "v"(W.w4c));
    asm volatile("" :: "v"(W.wih01), "v"(W.wih23), "v"(W.wih4),
                       "v"(W.b01), "v"(W.b23), "v"(W.b4));
}

template <int CTRL>
__device__ __forceinline__ float dpp_f(float v) {
    // old=0 + bound_ctrl + full masks -> GCNDPPCombine fuses into v_add_f32_dpp
    return __int_as_float(__builtin_amdgcn_update_dpp(
        0, __float_as_int(v), CTRL, 0xF, 0xF, true));
}

#define QP_XOR1 0xB1   // quad_perm [1,0,3,2]
#define QP_XOR2 0x4E   // quad_perm [2,3,0,1]
#define ROR4   0x124   // row_ror:4  (within 16-lane row)
#define ROR8   0x128   // row_ror:8

// One timestep, both batches. h0..h4 = h_pair for the 5 owned values.
// Per-batch arithmetic identical to R16: init, k=0..4 serial, fold C1, C2.
template <int C1, int C2>
__device__ __forceinline__ void step(v2f xp, v2f& h0, v2f& h1, v2f& h2,
                                     v2f& h3, v2f& h4, const WRole& W) {
    v2f a0 = __builtin_elementwise_fma(xp, W.wih01.xx, W.b01.xx);
    v2f a1 = __builtin_elementwise_fma(xp, W.wih01.yy, W.b01.yy);
    v2f a2 = __builtin_elementwise_fma(xp, W.wih23.xx, W.b23.xx);
    v2f a3 = __builtin_elementwise_fma(xp, W.wih23.yy, W.b23.yy);
    v2f a4 = __builtin_elementwise_fma(xp, W.wih4.xx,  W.b4.xx);

#define MK(HS, W0, W1, W2, W3, W4)                         \
    a0 = __builtin_elementwise_fma(HS, W0, a0);            \
    a1 = __builtin_elementwise_fma(HS, W1, a1);            \
    a2 = __builtin_elementwise_fma(HS, W2, a2);            \
    a3 = __builtin_elementwise_fma(HS, W3, a3);            \
    a4 = __builtin_elementwise_fma(HS, W4, a4);
    MK(h0, W.w01[0].xx, W.w01[1].xx, W.w01[2].xx, W.w01[3].xx, W.w01[4].xx)
    MK(h1, W.w01[0].yy, W.w01[1].yy, W.w01[2].yy, W.w01[3].yy, W.w01[4].yy)
    MK(h2, W.w23[0].xx, W.w23[1].xx, W.w23[2].xx, W.w23[3].xx, W.w23[4].xx)
    MK(h3, W.w23[0].yy, W.w23[1].yy, W.w23[2].yy, W.w23[3].yy, W.w23[4].yy)
    MK(h4, W.w4a.xx,    W.w4a.yy,    W.w4b.xx,    W.w4b.yy,    W.w4c.xx)
#undef MK

    // folds on the 10 scalar halves (u = even batch, p = odd batch)
    float u0 = a0.x, p0 = a0.y, u1 = a1.x, p1 = a1.y, u2 = a2.x, p2 = a2.y,
          u3 = a3.x, p3 = a3.y, u4 = a4.x, p4 = a4.y;
    {
        float t0 = dpp_f<C1>(u0), s0 = dpp_f<C1>(p0),
              t1 = dpp_f<C1>(u1), s1 = dpp_f<C1>(p1),
              t2 = dpp_f<C1>(u2), s2 = dpp_f<C1>(p2),
              t3 = dpp_f<C1>(u3), s3 = dpp_f<C1>(p3),
              t4 = dpp_f<C1>(u4), s4 = dpp_f<C1>(p4);
        u0 += t0; p0 += s0; u1 += t1; p1 += s1; u2 += t2; p2 += s2;
        u3 += t3; p3 += s3; u4 += t4; p4 += s4;
    }
    {
        float t0 = dpp_f<C2>(u0), s0 = dpp_f<C2>(p0),
              t1 = dpp_f<C2>(u1), s1 = dpp_f<C2>(p1),
              t2 = dpp_f<C2>(u2), s2 = dpp_f<C2>(p2),
              t3 = dpp_f<C2>(u3), s3 = dpp_f<C2>(p3),
              t4 = dpp_f<C2>(u4), s4 = dpp_f<C2>(p4);
        u0 += t0; p0 += s0; u1 += t1; p1 += s1; u2 += t2; p2 += s2;
        u3 += t3; p3 += s3; u4 += t4; p4 += s4;
    }

    const v2f z = {0.f, 0.f};
    h0 = __builtin_elementwise_max((v2f){u0, p0}, z);   // v_pk_max_f32
    h1 = __builtin_elementwise_max((v2f){u1, p1}, z);
    h2 = __builtin_elementwise_max((v2f){u2, p2}, z);
    h3 = __builtin_elementwise_max((v2f){u3, p3}, z);
    h4 = __builtin_elementwise_max((v2f){u4, p4}, z);
}

__global__ void
__attribute__((amdgpu_flat_work_group_size(64, 64), amdgpu_waves_per_eu(1, 1)))
rnn_os_kernel(const float* __restrict__ x,
              const float* __restrict__ W_ih,
              const float* __restrict__ W_hh,
              const float* __restrict__ b_ih,
              const float* __restrict__ b_hh,
              const float* __restrict__ fc_w,
              const float* __restrict__ fc_b,
              float* __restrict__ out) {
    const int tid = blockIdx.x * 64 + threadIdx.x;
    const int pg  = tid >> 4;     // batch-pair group: batches 2pg, 2pg+1
    const int gl  = tid & 15;     // lane in 16-lane group
    const int a   = gl >> 2;      // quad index
    const int bq  = gl & 3;       // position in quad

    const bool eact = (bq == 0);  // even steps: reduction over bq
    const bool oact = (a == 0);   // odd steps:  reduction over a

    WRole We, Wo;
#define WLOAD(W, RB, CB, ACT)                                                 \
    { const int rb = (RB), cb = (CB);                                         \
      for (int r = 0; r < 5; ++r) {                                           \
          (W).w01[r] = (v2f){ W_hh[(rb + r) * 20 + cb + 0],                   \
                              W_hh[(rb + r) * 20 + cb + 1] };                 \
          (W).w23[r] = (v2f){ W_hh[(rb + r) * 20 + cb + 2],                   \
                              W_hh[(rb + r) * 20 + cb + 3] };                 \
      }                                                                       \
      (W).w4a = (v2f){ W_hh[(rb + 0) * 20 + cb + 4],                          \
                       W_hh[(rb + 1) * 20 + cb + 4] };                        \
      (W).w4b = (v2f){ W_hh[(rb + 2) * 20 + cb + 4],                          \
                       W_hh[(rb + 3) * 20 + cb + 4] };                        \
      (W).w4c = (v2f){ W_hh[(rb + 4) * 20 + cb + 4],                          \
                       W_hh[(rb + 4) * 20 + cb + 4] };                        \
      const float* pw = W_ih + rb;                                            \
      const float* p1 = b_ih + rb;                                            \
      const float* p2 = b_hh + rb;                                            \
      (W).wih01 = (v2f){ (ACT) ? pw[0] : 0.f, (ACT) ? pw[1] : 0.f };          \
      (W).wih23 = (v2f){ (ACT) ? pw[2] : 0.f, (ACT) ? pw[3] : 0.f };          \
      (W).wih4  = (v2f){ (ACT) ? pw[4] : 0.f, (ACT) ? pw[4] : 0.f };          \
      (W).b01 = (v2f){ (ACT) ? (p1[0] + p2[0]) : 0.f,                         \
                       (ACT) ? (p1[1] + p2[1]) : 0.f };                       \
      (W).b23 = (v2f){ (ACT) ? (p1[2] + p2[2]) : 0.f,                         \
                       (ACT) ? (p1[3] + p2[3]) : 0.f };                       \
      (W).b4  = (v2f){ (ACT) ? (p1[4] + p2[4]) : 0.f,                         \
                       (ACT) ? (p1[4] + p2[4]) : 0.f }; }
    WLOAD(We, a * 5,  bq * 5, eact)   // even: rows a-group x cols bq-group
    WLOAD(Wo, bq * 5, a * 5,  oact)   // odd:  rows bq-group x cols a-group
#undef WLOAD

    pinw(We); pinw(Wo);

    v2f h0 = {0.f, 0.f}, h1 = {0.f, 0.f}, h2 = {0.f, 0.f},
        h3 = {0.f, 0.f}, h4 = {0.f, 0.f};

    const float* __restrict__ xbE = x + (size_t)(2 * pg) * TT;
    const float* __restrict__ xbO = xbE + TT;

#define STEP_E(XP) step<QP_XOR1, QP_XOR2>(XP, h0, h1, h2, h3, h4, We);
#define STEP_O(XP) step<ROR4,    ROR8   >(XP, h0, h1, h2, h3, h4, Wo);
#define RUN4(QE, QO) {                                  \
        v2f x0 = {QE.x, QO.x}; STEP_E(x0)               \
        v2f x1 = {QE.y, QO.y}; STEP_O(x1)               \
        v2f x2 = {QE.z, QO.z}; STEP_E(x2)               \
        v2f x3 = {QE.w, QO.w}; STEP_O(x3) }

    // 8-step loop body, 2 float4 per stream double-buffered.
    float4 AE = *(const float4*)(xbE);
    float4 AO = *(const float4*)(xbO);
    float4 BE = *(const float4*)(xbE + 4);
    float4 BO = *(const float4*)(xbO + 4);

    for (int it = 0; it < 124; ++it) {
        const int p = it * 8;
        RUN4(AE, AO)                          // steps p .. p+3
        AE = *(const float4*)(xbE + p + 8);
        AO = *(const float4*)(xbO + p + 8);
        RUN4(BE, BO)                          // steps p+4 .. p+7
        BE = *(const float4*)(xbE + p + 12);
        BO = *(const float4*)(xbO + p + 12);
    }
    // it=123 loaded steps 992..995 (A) and 996..999 (B)
    RUN4(AE, AO)                              // steps 992..995
    RUN4(BE, BO)                              // steps 996..999

#undef RUN4
#undef STEP_E
#undef STEP_O

    keepw(We); keepw(Wo);

    // After step 999 (odd role): lane (a,bq) holds h[5bq..5bq+4] pairs,
    // replicated over a. Mask fc weights to a==0, dot per half, reduce.
    float dx, dy;
    {
        const float* pf = fc_w + bq * 5;
        float f0 = oact ? pf[0] : 0.f, f1 = oact ? pf[1] : 0.f;
        float f2 = oact ? pf[2] : 0.f, f3 = oact ? pf[3] : 0.f;
        float f4 = oact ? pf[4] : 0.f;
        dx = h0.x * f0;
        dx = __builtin_fmaf(h1.x, f1, dx);
        dx = __builtin_fmaf(h2.x, f2, dx);
        dx = __builtin_fmaf(h3.x, f3, dx);
        dx = __builtin_fmaf(h4.x, f4, dx);
        dy = h0.y * f0;
        dy = __builtin_fmaf(h1.y, f1, dy);
        dy = __builtin_fmaf(h2.y, f2, dy);
        dy = __builtin_fmaf(h3.y, f3, dy);
        dy = __builtin_fmaf(h4.y, f4, dy);
    }
    dx += __shfl_xor(dx, 1, 16);  dy += __shfl_xor(dy, 1, 16);
    dx += __shfl_xor(dx, 2, 16);  dy += __shfl_xor(dy, 2, 16);
    dx += __shfl_xor(dx, 4, 16);  dy += __shfl_xor(dy, 4, 16);
    dx += __shfl_xor(dx, 8, 16);  dy += __shfl_xor(dy, 8, 16);

    if (gl == 0) {
        float2 o = { dx + fc_b[0], dy + fc_b[0] };
        *(float2*)(out + 2 * pg) = o;
    }
}

extern "C" void kernel_launch(void* const* d_in, const int* in_sizes, int n_in,
                              void* d_out, int out_size, void* d_ws, size_t ws_size,
                              hipStream_t stream) {
    const float* x    = (const float*)d_in[0];
    const float* W_ih = (const float*)d_in[1];
    const float* W_hh = (const float*)d_in[2];
    const float* b_ih = (const float*)d_in[3];
    const float* b_hh = (const float*)d_in[4];
    const float* fc_w = (const float*)d_in[5];
    const float* fc_b = (const float*)d_in[6];
    float* out = (float*)d_out;

    // 2048 batch-pairs * 16 lanes = 32768 threads; 64-thread blocks ->
    // 512 single-wave blocks = 2 per CU (separate SIMDs).
    const int block = 64;
    const int grid  = (2048 * 16) / block;  // 512 blocks
    rnn_os_kernel<<<grid, block, 0, stream>>>(x, W_ih, W_hh, b_ih, b_hh,
                                              fc_w, fc_b, out);
}

// Round 8
// 147.122 us; speedup vs baseline: 1.6952x; 1.6808x over previous
//
#include <hip/hip_runtime.h>

// RNN: h_{t+1} = relu(x_t*W_ih^T + b_ih + b_hh + W_hh·h_t), out = fc(h_T).
// B=4096, T=1000, H=20.  16 lanes/batch, 1024 waves = 1 per SIMD.
//
// R23: R16 structure restored (best harness: 146.7us) + r4 k-pairing.
// Session model (fits R16..R22): harness time = total VALU instrs / ~230G
// instr/s sustained power cap (R17: rocprof -40% -> harness +4%, clock
// dropped to hold the rate); low-occupancy escapes the cap but is wall-
// bound at ~6-10cy/instr single-wave cadence (all >=199us). Only lever:
// instruction count at full occupancy. R16 = 33/step (8.25/batch) = at cap.
// Cut: row-4's 5 scalar FMAs + init -> 2 pk_fma vs h01/h23 pairs (direct
// pair operands, no splat) + 1 horizontal add: 33 -> ~31/step.

#define TT 1000

typedef float v2f __attribute__((ext_vector_type(2)));

// One role's weights/bias. Per k-column: rows (r0,r1),(r2,r3) as v2f.
// Row 4 k-paired: w4ab[0]=(w[4][k0],w[4][k1]), w4ab[1]=(k2,k3), w4e=k4.
struct Role {
    v2f c01[5], c23[5];
    v2f w4ab[2];
    float w4e;
    v2f wih01, wih23; float wih4;
    v2f b01, b23;     float b4;
};

#define PIN(v)  asm volatile("" : "+v"(v))
__device__ __forceinline__ void pinr(Role& R) {
    PIN(R.c01[0]); PIN(R.c01[1]); PIN(R.c01[2]); PIN(R.c01[3]); PIN(R.c01[4]);
    PIN(R.c23[0]); PIN(R.c23[1]); PIN(R.c23[2]); PIN(R.c23[3]); PIN(R.c23[4]);
    PIN(R.w4ab[0]); PIN(R.w4ab[1]); PIN(R.w4e);
    PIN(R.wih01); PIN(R.wih23); PIN(R.wih4);
    PIN(R.b01); PIN(R.b23); PIN(R.b4);
}
__device__ __forceinline__ void keepr(const Role& R) {
    asm volatile("" :: "v"(R.c01[0]), "v"(R.c01[1]), "v"(R.c01[2]),
                       "v"(R.c01[3]), "v"(R.c01[4]));
    asm volatile("" :: "v"(R.c23[0]), "v"(R.c23[1]), "v"(R.c23[2]),
                       "v"(R.c23[3]), "v"(R.c23[4]));
    asm volatile("" :: "v"(R.w4ab[0]), "v"(R.w4ab[1]), "v"(R.w4e));
    asm volatile("" :: "v"(R.wih01), "v"(R.wih23), "v"(R.wih4),
                       "v"(R.b01), "v"(R.b23), "v"(R.b4));
}

template <int CTRL>
__device__ __forceinline__ float dpp_f(float v) {
    // old=0 + bound_ctrl + full masks -> GCNDPPCombine fuses into v_add_f32_dpp
    return __int_as_float(__builtin_amdgcn_update_dpp(
        0, __float_as_int(v), CTRL, 0xF, 0xF, true));
}

#define QP_XOR1 0xB1   // quad_perm [1,0,3,2]
#define QP_XOR2 0x4E   // quad_perm [2,3,0,1]
#define ROR4   0x124   // row_ror:4  (within 16-lane row)
#define ROR8   0x128   // row_ror:8

// One timestep. xp = v2f holding 2 consecutive x's; HALF picks which one.
template <int HALF, int C1, int C2>
__device__ __forceinline__ void step(v2f xp, v2f& h01, v2f& h23, float& h4,
                                     const Role& R) {
    const v2f xs = (HALF == 0) ? xp.xx : xp.yy;     // op_sel-able splat
    const float xt = (HALF == 0) ? xp.x : xp.y;

    // rows 0-3: init then 5 k-columns (pk_fma, splat operands)
    v2f A01 = __builtin_elementwise_fma(xs, R.wih01, R.b01);
    v2f A23 = __builtin_elementwise_fma(xs, R.wih23, R.b23);

    // row 4, k-paired: P4 = (init4 + h0*w40 + h2*w42, h4*w44 + h1*w41 + h3*w43)
    float i4 = __builtin_fmaf(xt, R.wih4, R.b4);
    float t4 = h4 * R.w4e;
    v2f P4 = {i4, t4};
    P4 = __builtin_elementwise_fma(h01, R.w4ab[0], P4);
    P4 = __builtin_elementwise_fma(h23, R.w4ab[1], P4);

    const v2f h4s = {h4, h4};
#define KCOL(hs, k)                                                 \
    A01 = __builtin_elementwise_fma(hs, R.c01[k], A01);             \
    A23 = __builtin_elementwise_fma(hs, R.c23[k], A23);
    KCOL(h01.xx, 0)
    KCOL(h01.yy, 1)
    KCOL(h23.xx, 2)
    KCOL(h23.yy, 3)
    KCOL(h4s,    4)
#undef KCOL

    // folds on the five 32-bit partials (breadth-first)
    float b0 = A01.x, b1 = A01.y, b2 = A23.x, b3 = A23.y;
    float b4 = P4.x + P4.y;
    {
        float t0 = dpp_f<C1>(b0), t1 = dpp_f<C1>(b1), t2 = dpp_f<C1>(b2),
              t3 = dpp_f<C1>(b3), u4 = dpp_f<C1>(b4);
        b0 += t0; b1 += t1; b2 += t2; b3 += t3; b4 += u4;
    }
    {
        float t0 = dpp_f<C2>(b0), t1 = dpp_f<C2>(b1), t2 = dpp_f<C2>(b2),
              t3 = dpp_f<C2>(b3), u4 = dpp_f<C2>(b4);
        b0 += t0; b1 += t1; b2 += t2; b3 += t3; b4 += u4;
    }

    const v2f z = {0.f, 0.f};
    v2f r01 = {b0, b1};
    v2f r23 = {b2, b3};
    h01 = __builtin_elementwise_max(r01, z);   // v_pk_max_f32
    h23 = __builtin_elementwise_max(r23, z);
    h4  = fmaxf(b4, 0.f);
}

__global__ void
__attribute__((amdgpu_flat_work_group_size(64, 64), amdgpu_waves_per_eu(1, 1)))
rnn_os_kernel(const float* __restrict__ x,
              const float* __restrict__ W_ih,
              const float* __restrict__ W_hh,
              const float* __restrict__ b_ih,
              const float* __restrict__ b_hh,
              const float* __restrict__ fc_w,
              const float* __restrict__ fc_b,
              float* __restrict__ out) {
    const int tid = blockIdx.x * 64 + threadIdx.x;
    const int b   = tid >> 4;     // batch element
    const int gl  = tid & 15;     // lane in 16-lane group
    const int a   = gl >> 2;      // quad index
    const int bq  = gl & 3;       // position in quad

    const bool eact = (bq == 0);  // even steps: reduction over bq
    const bool oact = (a == 0);   // odd steps:  reduction over a

    Role Re, Ro;
#define RLOAD(R, RB, CB, ACT)                                                 \
    { const int rb = (RB), cb = (CB);                                         \
      for (int k = 0; k < 5; ++k) {                                           \
          (R).c01[k] = (v2f){ W_hh[(rb + 0) * 20 + cb + k],                   \
                              W_hh[(rb + 1) * 20 + cb + k] };                 \
          (R).c23[k] = (v2f){ W_hh[(rb + 2) * 20 + cb + k],                   \
                              W_hh[(rb + 3) * 20 + cb + k] };                 \
      }                                                                       \
      (R).w4ab[0] = (v2f){ W_hh[(rb + 4) * 20 + cb + 0],                      \
                           W_hh[(rb + 4) * 20 + cb + 1] };                    \
      (R).w4ab[1] = (v2f){ W_hh[(rb + 4) * 20 + cb + 2],                      \
                           W_hh[(rb + 4) * 20 + cb + 3] };                    \
      (R).w4e     =        W_hh[(rb + 4) * 20 + cb + 4];                      \
      const float* pw = W_ih + rb;                                            \
      const float* p1 = b_ih + rb;                                            \
      const float* p2 = b_hh + rb;                                            \
      (R).wih01 = (v2f){ (ACT) ? pw[0] : 0.f, (ACT) ? pw[1] : 0.f };          \
      (R).wih23 = (v2f){ (ACT) ? pw[2] : 0.f, (ACT) ? pw[3] : 0.f };          \
      (R).wih4  =        (ACT) ? pw[4] : 0.f;                                 \
      (R).b01 = (v2f){ (ACT) ? (p1[0] + p2[0]) : 0.f,                         \
                       (ACT) ? (p1[1] + p2[1]) : 0.f };                       \
      (R).b23 = (v2f){ (ACT) ? (p1[2] + p2[2]) : 0.f,                         \
                       (ACT) ? (p1[3] + p2[3]) : 0.f };                       \
      (R).b4  =        (ACT) ? (p1[4] + p2[4]) : 0.f; }
    RLOAD(Re, a * 5,  bq * 5, eact)   // even: rows a-group x cols bq-group
    RLOAD(Ro, bq * 5, a * 5,  oact)   // odd:  rows bq-group x cols a-group
#undef RLOAD

    pinr(Re); pinr(Ro);

    v2f h01 = {0.f, 0.f}, h23 = {0.f, 0.f};
    float h4 = 0.f;

    const float* __restrict__ xb = x + (size_t)b * TT;

    // --- 40-step register blocks (10 float4 each), double-buffered (R16).
#define LOAD10(P, off)                                  \
    P##0 = *(const float4*)(xb + (off));                \
    P##1 = *(const float4*)(xb + (off) + 4);            \
    P##2 = *(const float4*)(xb + (off) + 8);            \
    P##3 = *(const float4*)(xb + (off) + 12);           \
    P##4 = *(const float4*)(xb + (off) + 16);           \
    P##5 = *(const float4*)(xb + (off) + 20);           \
    P##6 = *(const float4*)(xb + (off) + 24);           \
    P##7 = *(const float4*)(xb + (off) + 28);           \
    P##8 = *(const float4*)(xb + (off) + 32);           \
    P##9 = *(const float4*)(xb + (off) + 36);

#define STEP_E(xp, H) step<H, QP_XOR1, QP_XOR2>(xp, h01, h23, h4, Re);
#define STEP_O(xp, H) step<H, ROR4,    ROR8   >(xp, h01, h23, h4, Ro);
#define RUN4(Q) {                                       \
        const v2f qlo = {Q.x, Q.y};                     \
        const v2f qhi = {Q.z, Q.w};                     \
        STEP_E(qlo, 0) STEP_O(qlo, 1)                   \
        STEP_E(qhi, 0) STEP_O(qhi, 1) }
#define RUN40(P) RUN4(P##0) RUN4(P##1) RUN4(P##2) RUN4(P##3) RUN4(P##4) \
                 RUN4(P##5) RUN4(P##6) RUN4(P##7) RUN4(P##8) RUN4(P##9)

    float4 A0, A1, A2, A3, A4, A5, A6, A7, A8, A9;
    float4 B0, B1, B2, B3, B4, B5, B6, B7, B8, B9;
    LOAD10(A, 0)    // steps 0..39
    LOAD10(B, 40)   // steps 40..79

    // 12 iterations x 80 steps = 960, then a 40-step tail from A.
    for (int it = 0; it < 12; ++it) {
        const int base = it * 80;
        const int nb = (it < 11) ? base + 120 : 960;  // clamped; stale unused

        RUN40(A)                    // steps base .. base+39
        LOAD10(A, base + 80)        // it=11 loads steps 960..999 (the tail)
        RUN40(B)                    // steps base+40 .. base+79
        LOAD10(B, nb)
    }
    RUN40(A)                        // steps 960..999

#undef RUN40
#undef RUN4
#undef STEP_E
#undef STEP_O
#undef LOAD10

    keepr(Re); keepr(Ro);

    // After step 999 (odd role), lane (a,bq) holds h[bq-slice] replicated
    // over a. Mask fc weights to a==0 lanes, dot, reduce across the group.
    float dot;
    {
        const float* pf = fc_w + bq * 5;
        float f0 = oact ? pf[0] : 0.f, f1 = oact ? pf[1] : 0.f;
        float f2 = oact ? pf[2] : 0.f, f3 = oact ? pf[3] : 0.f;
        float f4 = oact ? pf[4] : 0.f;
        dot = h01.x * f0;
        dot = __builtin_fmaf(h01.y, f1, dot);
        dot = __builtin_fmaf(h23.x, f2, dot);
        dot = __builtin_fmaf(h23.y, f3, dot);
        dot = __builtin_fmaf(h4,    f4, dot);
    }
    dot += __shfl_xor(dot, 1, 16);
    dot += __shfl_xor(dot, 2, 16);
    dot += __shfl_xor(dot, 4, 16);
    dot += __shfl_xor(dot, 8, 16);

    if (gl == 0)
        out[b] = dot + fc_b[0];
}

extern "C" void kernel_launch(void* const* d_in, const int* in_sizes, int n_in,
                              void* d_out, int out_size, void* d_ws, size_t ws_size,
                              hipStream_t stream) {
    const float* x    = (const float*)d_in[0];
    const float* W_ih = (const float*)d_in[1];
    const float* W_hh = (const float*)d_in[2];
    const float* b_ih = (const float*)d_in[3];
    const float* b_hh = (const float*)d_in[4];
    const float* fc_w = (const float*)d_in[5];
    const float* fc_b = (const float*)d_in[6];
    float* out = (float*)d_out;

    // 4096 batches * 16 lanes = 65536 threads; 64-thread blocks -> 1024
    // single-wave blocks, one per SIMD.
    const int block = 64;
    const int grid  = (4096 * 16) / block;  // 1024 blocks
    rnn_os_kernel<<<grid, block, 0, stream>>>(x, W_ih, W_hh, b_ih, b_hh,
                                              fc_w, fc_b, out);
}